// Round 1
// baseline (134.854 us; speedup 1.0000x reference)
//
#include <hip/hip_runtime.h>
#include <hip/hip_bf16.h>

#define CCH 256
#define MM  32768

typedef float    f32x4  __attribute__((ext_vector_type(4)));
typedef _Float16 f16x8  __attribute__((ext_vector_type(8)));
typedef short    bf16x8 __attribute__((ext_vector_type(8)));

__device__ inline unsigned short f2bf(float f) {
  union { float f; unsigned int u; } v; v.f = f;
  unsigned int u = v.u;
  unsigned int r = (u + 0x7fffu + ((u >> 16) & 1u)) >> 16;
  return (unsigned short)r;
}

__device__ inline float dot4(float4 a, const float* b) {
  return a.x * b[0] + a.y * b[1] + a.z * b[2] + a.w * b[3];
}

// ---------------------------------------------------------------------------
// K1: split-K Gram  G_partial = X_chunk * X_chunk^T  (fp16 two-term split)
// grid = 2*spb blocks, 512 threads (8 waves). Each block: full 256x256 partial
// over an M-chunk of Mc columns. Also accumulates partial row-sums s.
// ---------------------------------------------------------------------------
__global__ __launch_bounds__(512) void gram_kernel(const float* __restrict__ x,
    float* __restrict__ gpart, float* __restrict__ spart, int Mc, int spb) {
  __shared__ _Float16 hiL[CCH * 32];
  __shared__ _Float16 loL[CCH * 32];
  const int t = threadIdx.x;
  const int b = blockIdx.x;
  const int n = b / spb, ks = b % spb;
  const float* X = x + (size_t)n * CCH * MM + (size_t)ks * Mc;
  const int c = t >> 1, mo = (t & 1) << 4;
  const float* px = X + (size_t)c * MM + mo;
  const int stages = Mc >> 5;
  const int l = t & 63, w = t >> 6;
  const int i0 = w << 1;

  f32x4 acc[2][16];
  #pragma unroll
  for (int ii = 0; ii < 2; ++ii)
    #pragma unroll
    for (int jt = 0; jt < 16; ++jt)
      acc[ii][jt] = (f32x4){0.f, 0.f, 0.f, 0.f};

  float4 p0 = *(const float4*)(px + 0);
  float4 p1 = *(const float4*)(px + 4);
  float4 p2 = *(const float4*)(px + 8);
  float4 p3 = *(const float4*)(px + 12);
  float ssum = 0.f;

  // swizzled LDS slots for this thread's two 8-half chunks (16B granules)
  const int kb0 = (t & 1) * 2;
  const int sw  = (c >> 1) & 3;
  _Float16* hd0 = &hiL[c * 32 + ((kb0 + 0) ^ sw) * 8];
  _Float16* hd1 = &hiL[c * 32 + ((kb0 + 1) ^ sw) * 8];
  _Float16* ld0 = &loL[c * 32 + ((kb0 + 0) ^ sw) * 8];
  _Float16* ld1 = &loL[c * 32 + ((kb0 + 1) ^ sw) * 8];

  for (int s = 0; s < stages; ++s) {
    float fv[16];
    fv[0] = p0.x; fv[1] = p0.y; fv[2]  = p0.z; fv[3]  = p0.w;
    fv[4] = p1.x; fv[5] = p1.y; fv[6]  = p1.z; fv[7]  = p1.w;
    fv[8] = p2.x; fv[9] = p2.y; fv[10] = p2.z; fv[11] = p2.w;
    fv[12] = p3.x; fv[13] = p3.y; fv[14] = p3.z; fv[15] = p3.w;
    f16x8 h0, h1, lo0, lo1;
    #pragma unroll
    for (int e = 0; e < 8; ++e) {
      float a = fv[e]; ssum += a;
      _Float16 hh = (_Float16)a;
      h0[e] = hh; lo0[e] = (_Float16)(a - (float)hh);
    }
    #pragma unroll
    for (int e = 0; e < 8; ++e) {
      float a = fv[8 + e]; ssum += a;
      _Float16 hh = (_Float16)a;
      h1[e] = hh; lo1[e] = (_Float16)(a - (float)hh);
    }
    *(f16x8*)hd0 = h0;  *(f16x8*)hd1 = h1;
    *(f16x8*)ld0 = lo0; *(f16x8*)ld1 = lo1;
    if (s + 1 < stages) {                 // prefetch next stage into regs
      const float* pn = px + (size_t)(s + 1) * 32;
      p0 = *(const float4*)(pn + 0);
      p1 = *(const float4*)(pn + 4);
      p2 = *(const float4*)(pn + 8);
      p3 = *(const float4*)(pn + 12);
    }
    __syncthreads();
    f16x8 Ahi[2], Alo[2];
    #pragma unroll
    for (int ii = 0; ii < 2; ++ii) {
      int cr = (i0 + ii) * 16 + (l & 15);
      int sl = (l >> 4) ^ ((cr >> 1) & 3);
      int idx = cr * 32 + sl * 8;
      Ahi[ii] = *(const f16x8*)&hiL[idx];
      Alo[ii] = *(const f16x8*)&loL[idx];
    }
    #pragma unroll
    for (int jt = 0; jt < 16; ++jt) {
      int cr = jt * 16 + (l & 15);
      int sl = (l >> 4) ^ ((cr >> 1) & 3);
      int idx = cr * 32 + sl * 8;
      f16x8 Bhi = *(const f16x8*)&hiL[idx];
      f16x8 Blo = *(const f16x8*)&loL[idx];
      #pragma unroll
      for (int ii = 0; ii < 2; ++ii) {
        acc[ii][jt] = __builtin_amdgcn_mfma_f32_16x16x32_f16(Ahi[ii], Bhi, acc[ii][jt], 0, 0, 0);
        acc[ii][jt] = __builtin_amdgcn_mfma_f32_16x16x32_f16(Ahi[ii], Blo, acc[ii][jt], 0, 0, 0);
        acc[ii][jt] = __builtin_amdgcn_mfma_f32_16x16x32_f16(Alo[ii], Bhi, acc[ii][jt], 0, 0, 0);
      }
    }
    __syncthreads();
  }
  float* gp = gpart + ((size_t)n * spb + ks) * 65536;
  #pragma unroll
  for (int ii = 0; ii < 2; ++ii)
    #pragma unroll
    for (int jt = 0; jt < 16; ++jt) {
      int col = jt * 16 + (l & 15);
      int rb  = (i0 + ii) * 16 + ((l >> 4) << 2);
      #pragma unroll
      for (int r = 0; r < 4; ++r)
        gp[(rb + r) * 256 + col] = acc[ii][jt][r];
    }
  ssum += __shfl_xor(ssum, 1);
  if ((t & 1) == 0) spart[((size_t)n * spb + ks) * 256 + c] = ssum;
}

// ---------------------------------------------------------------------------
// K1b: reduce split-K partials -> G (2x256x256), s (2x256)
// ---------------------------------------------------------------------------
__global__ __launch_bounds__(256) void reduce_kernel(const float* __restrict__ gpart,
    const float* __restrict__ spart, float* __restrict__ G, float* __restrict__ sv,
    int spb) {
  int idx = blockIdx.x * 256 + threadIdx.x;
  if (idx < 2 * 65536) {
    int n = idx >> 16, e = idx & 65535;
    const float* p = gpart + (size_t)n * spb * 65536 + e;
    float s = 0.f;
    for (int k = 0; k < spb; ++k) s += p[(size_t)k * 65536];
    G[idx] = s;
  } else {
    int r = idx - 2 * 65536;          // 0..511
    int n = r >> 8, cc = r & 255;
    const float* p = spart + (size_t)n * spb * 256 + cc;
    float s = 0.f;
    for (int k = 0; k < spb; ++k) s += p[k * 256];
    sv[r] = s;
  }
}

// ---------------------------------------------------------------------------
// K2: per (n, j): S row from G/s + weights, softmax, Bmat row (bf16), bb.
// grid = 512 blocks (n = b>>8, j = b&255), 256 threads (t = channel index).
// ---------------------------------------------------------------------------
__global__ __launch_bounds__(256) void attn_kernel(const float* __restrict__ G,
    const float* __restrict__ sv_g,
    const float* __restrict__ Wq, const float* __restrict__ bq,
    const float* __restrict__ Wk, const float* __restrict__ bk,
    const float* __restrict__ Wv, const float* __restrict__ bv,
    unsigned short* __restrict__ Bm, float* __restrict__ bb) {
  __shared__ float wq_s[256], s_s[256], t1_s[256], att_s[256];
  __shared__ float red_s[4];
  const int t = threadIdx.x;
  const int n = blockIdx.x >> 8, j = blockIdx.x & 255;
  wq_s[t] = Wq[j * 256 + t];
  s_s[t]  = sv_g[n * 256 + t];
  __syncthreads();
  // phase A: t1[t] = sum_c wq[c] * G[c][t]  (G symmetric -> read row t)
  {
    const float4* Gr = (const float4*)(G + (size_t)n * 65536 + (size_t)t * 256);
    float a = 0.f;
    #pragma unroll 4
    for (int c4 = 0; c4 < 64; ++c4) a += dot4(Gr[c4], &wq_s[c4 * 4]);
    t1_s[t] = a;
  }
  __syncthreads();
  // phase B: S[j][t]
  float acc1 = 0.f, acc2 = 0.f, qs = 0.f;
  {
    const float4* Wkr = (const float4*)(Wk + (size_t)t * 256);
    #pragma unroll 4
    for (int c4 = 0; c4 < 64; ++c4) {
      float4 wk4 = Wkr[c4];
      const float* w4 = &wq_s[c4 * 4];
      const float* s4 = &s_s[c4 * 4];
      acc1 += dot4(wk4, &t1_s[c4 * 4]);
      acc2 += dot4(wk4, s4);
      qs   += w4[0] * s4[0] + w4[1] * s4[1] + w4[2] * s4[2] + w4[3] * s4[3];
    }
  }
  const float bqj = bq[j], bkt = bk[t];
  float S = acc1 + bqj * acc2 + qs * bkt + 32768.0f * bqj * bkt;
  // softmax over t (block of 256 = 4 waves)
  float mx = S;
  #pragma unroll
  for (int o = 1; o < 64; o <<= 1) mx = fmaxf(mx, __shfl_xor(mx, o));
  if ((t & 63) == 0) red_s[t >> 6] = mx;
  __syncthreads();
  mx = fmaxf(fmaxf(red_s[0], red_s[1]), fmaxf(red_s[2], red_s[3]));
  float e = expf(S - mx);
  float sm = e;
  #pragma unroll
  for (int o = 1; o < 64; o <<= 1) sm += __shfl_xor(sm, o);
  __syncthreads();
  if ((t & 63) == 0) red_s[t >> 6] = sm;
  __syncthreads();
  sm = red_s[0] + red_s[1] + red_s[2] + red_s[3];
  att_s[t] = e / sm;
  __syncthreads();
  // phase C: Bmat row j (bf16) and bb[j]
  float bacc = 0.f, bbacc = 0.f;
  for (int cc = 0; cc < 256; ++cc) {
    float ac = att_s[cc];
    bacc  += ac * Wv[cc * 256 + t];
    bbacc += ac * bv[cc];
  }
  Bm[((size_t)(n * 256 + j)) * 256 + t] = f2bf(bacc);
  if (t == 0) bb[n * 256 + j] = bbacc;
}

// ---------------------------------------------------------------------------
// K3: out[n][m][j] = sum_c Bmat[j][c] * X[c][m] + bb[j]   (bf16 MFMA)
// grid = 1024 (n = b>>9, m-block of 64), 256 threads (4 waves, 16 m each).
// ---------------------------------------------------------------------------
__global__ __launch_bounds__(256) void out_kernel(const float* __restrict__ x,
    const unsigned short* __restrict__ Bm, const float* __restrict__ bb,
    float* __restrict__ out) {
  __shared__ unsigned short Bl[256 * 64];
  const int t = threadIdx.x;
  const int b = blockIdx.x;
  const int n = b >> 9, mb = b & 511;
  const int m0 = mb << 6;
  const int l = t & 63, w = t >> 6;
  f32x4 acc[16];
  #pragma unroll
  for (int jt = 0; jt < 16; ++jt) acc[jt] = (f32x4){0.f, 0.f, 0.f, 0.f};
  const unsigned short* Bmn = Bm + (size_t)n * 65536;
  const float* xn = x + (size_t)n * CCH * MM;
  const int mA = m0 + w * 16 + (l & 15);
  for (int ch = 0; ch < 4; ++ch) {
    #pragma unroll
    for (int it = 0; it < 8; ++it) {      // stage Bmat[:, ch*64 .. +64) bf16
      int i = it * 256 + t;
      int j = i >> 3, cb = i & 7;
      uint4 v = *(const uint4*)(Bmn + (size_t)j * 256 + ch * 64 + cb * 8);
      int slot = cb ^ (j & 7);
      *(uint4*)&Bl[j * 64 + slot * 8] = v;
    }
    __syncthreads();
    #pragma unroll
    for (int kk = 0; kk < 2; ++kk) {
      int cbase = ch * 64 + kk * 32 + (l >> 4) * 8;
      const float* xp = xn + (size_t)cbase * MM + mA;
      bf16x8 afrag;
      #pragma unroll
      for (int jj = 0; jj < 8; ++jj) {
        float v = xp[(size_t)jj * MM];
        afrag[jj] = (short)f2bf(v);
      }
      int cb2 = kk * 4 + (l >> 4);
      #pragma unroll
      for (int jt = 0; jt < 16; ++jt) {
        int jrow = jt * 16 + (l & 15);
        int slot = cb2 ^ (jrow & 7);
        bf16x8 bfrag = *(const bf16x8*)&Bl[jrow * 64 + slot * 8];
        acc[jt] = __builtin_amdgcn_mfma_f32_16x16x32_bf16(afrag, bfrag, acc[jt], 0, 0, 0);
      }
    }
    __syncthreads();
  }
  float* op = out + (size_t)n * MM * 256;
  const int mrb = m0 + w * 16 + ((l >> 4) << 2);
  #pragma unroll
  for (int jt = 0; jt < 16; ++jt) {
    int jcol = jt * 16 + (l & 15);
    float bias = bb[n * 256 + jcol];
    #pragma unroll
    for (int r = 0; r < 4; ++r)
      op[(size_t)(mrb + r) * 256 + jcol] = acc[jt][r] + bias;
  }
}

// ---------------------------------------------------------------------------
extern "C" void kernel_launch(void* const* d_in, const int* in_sizes, int n_in,
                              void* d_out, int out_size, void* d_ws, size_t ws_size,
                              hipStream_t stream) {
  (void)in_sizes; (void)n_in; (void)out_size;
  const float* x  = (const float*)d_in[0];
  const float* Wq = (const float*)d_in[1];
  const float* bq = (const float*)d_in[2];
  const float* Wk = (const float*)d_in[3];
  const float* bk = (const float*)d_in[4];
  const float* Wv = (const float*)d_in[5];
  const float* bv = (const float*)d_in[6];
  float* out = (float*)d_out;

  // split-K factor: largest power of two <= 128 whose workspace fits
  int spb = 128;
  while (spb > 1) {
    size_t need = (size_t)(2 * spb * (65536 + 256) + 2 * 65536 + 6 * 256) * 4
                + (size_t)2 * 65536 * 2;
    if (need <= ws_size) break;
    spb >>= 1;
  }
  float* wsf   = (float*)d_ws;
  float* gpart = wsf;
  float* spart = gpart + (size_t)2 * spb * 65536;
  float* G     = spart + (size_t)2 * spb * 256;
  float* sv    = G + 2 * 65536;
  float* bb    = sv + 2 * 256;
  unsigned short* Bm = (unsigned short*)(bb + 2 * 256);
  const int Mc = MM / spb;

  gram_kernel<<<dim3(2 * spb), dim3(512), 0, stream>>>(x, gpart, spart, Mc, spb);
  reduce_kernel<<<dim3((2 * 65536 + 512) / 256), dim3(256), 0, stream>>>(gpart, spart, G, sv, spb);
  attn_kernel<<<dim3(512), dim3(256), 0, stream>>>(G, sv, Wq, bq, Wk, bk, Wv, bv, Bm, bb);
  out_kernel<<<dim3(1024), dim3(256), 0, stream>>>(x, Bm, bb, out);
}

// Round 2
// 131.188 us; speedup vs baseline: 1.0279x; 1.0279x over previous
//
#include <hip/hip_runtime.h>
#include <hip/hip_bf16.h>

#define CCH 256
#define MM  32768

typedef float    f32x4  __attribute__((ext_vector_type(4)));
typedef _Float16 f16x8  __attribute__((ext_vector_type(8)));
typedef short    bf16x8 __attribute__((ext_vector_type(8)));

__device__ inline unsigned short f2bf(float f) {
  union { float f; unsigned int u; } v; v.f = f;
  unsigned int u = v.u;
  unsigned int r = (u + 0x7fffu + ((u >> 16) & 1u)) >> 16;
  return (unsigned short)r;
}

// ---------------------------------------------------------------------------
// K1: split-K Gram  G_partial = X_chunk * X_chunk^T  (fp16 two-term split)
// grid = 2*spb blocks, 512 threads (8 waves). Each block: full 256x256 partial
// over an M-chunk of Mc columns. Also accumulates partial row-sums s.
// ---------------------------------------------------------------------------
__global__ __launch_bounds__(512) void gram_kernel(const float* __restrict__ x,
    float* __restrict__ gpart, float* __restrict__ spart, int Mc, int spb) {
  __shared__ _Float16 hiL[CCH * 32];
  __shared__ _Float16 loL[CCH * 32];
  const int t = threadIdx.x;
  const int b = blockIdx.x;
  const int n = b / spb, ks = b % spb;
  const float* X = x + (size_t)n * CCH * MM + (size_t)ks * Mc;
  const int c = t >> 1, mo = (t & 1) << 4;
  const float* px = X + (size_t)c * MM + mo;
  const int stages = Mc >> 5;
  const int l = t & 63, w = t >> 6;
  const int i0 = w << 1;

  f32x4 acc[2][16];
  #pragma unroll
  for (int ii = 0; ii < 2; ++ii)
    #pragma unroll
    for (int jt = 0; jt < 16; ++jt)
      acc[ii][jt] = (f32x4){0.f, 0.f, 0.f, 0.f};

  float4 p0 = *(const float4*)(px + 0);
  float4 p1 = *(const float4*)(px + 4);
  float4 p2 = *(const float4*)(px + 8);
  float4 p3 = *(const float4*)(px + 12);
  float ssum = 0.f;

  // swizzled LDS slots for this thread's two 8-half chunks (16B granules)
  const int kb0 = (t & 1) * 2;
  const int sw  = (c >> 1) & 3;
  _Float16* hd0 = &hiL[c * 32 + ((kb0 + 0) ^ sw) * 8];
  _Float16* hd1 = &hiL[c * 32 + ((kb0 + 1) ^ sw) * 8];
  _Float16* ld0 = &loL[c * 32 + ((kb0 + 0) ^ sw) * 8];
  _Float16* ld1 = &loL[c * 32 + ((kb0 + 1) ^ sw) * 8];

  for (int s = 0; s < stages; ++s) {
    float fv[16];
    fv[0] = p0.x; fv[1] = p0.y; fv[2]  = p0.z; fv[3]  = p0.w;
    fv[4] = p1.x; fv[5] = p1.y; fv[6]  = p1.z; fv[7]  = p1.w;
    fv[8] = p2.x; fv[9] = p2.y; fv[10] = p2.z; fv[11] = p2.w;
    fv[12] = p3.x; fv[13] = p3.y; fv[14] = p3.z; fv[15] = p3.w;
    f16x8 h0, h1, lo0, lo1;
    #pragma unroll
    for (int e = 0; e < 8; ++e) {
      float a = fv[e]; ssum += a;
      _Float16 hh = (_Float16)a;
      h0[e] = hh; lo0[e] = (_Float16)(a - (float)hh);
    }
    #pragma unroll
    for (int e = 0; e < 8; ++e) {
      float a = fv[8 + e]; ssum += a;
      _Float16 hh = (_Float16)a;
      h1[e] = hh; lo1[e] = (_Float16)(a - (float)hh);
    }
    *(f16x8*)hd0 = h0;  *(f16x8*)hd1 = h1;
    *(f16x8*)ld0 = lo0; *(f16x8*)ld1 = lo1;
    if (s + 1 < stages) {                 // prefetch next stage into regs
      const float* pn = px + (size_t)(s + 1) * 32;
      p0 = *(const float4*)(pn + 0);
      p1 = *(const float4*)(pn + 4);
      p2 = *(const float4*)(pn + 8);
      p3 = *(const float4*)(pn + 12);
    }
    __syncthreads();
    f16x8 Ahi[2], Alo[2];
    #pragma unroll
    for (int ii = 0; ii < 2; ++ii) {
      int cr = (i0 + ii) * 16 + (l & 15);
      int sl = (l >> 4) ^ ((cr >> 1) & 3);
      int idx = cr * 32 + sl * 8;
      Ahi[ii] = *(const f16x8*)&hiL[idx];
      Alo[ii] = *(const f16x8*)&loL[idx];
    }
    #pragma unroll
    for (int jt = 0; jt < 16; ++jt) {
      int cr = jt * 16 + (l & 15);
      int sl = (l >> 4) ^ ((cr >> 1) & 3);
      int idx = cr * 32 + sl * 8;
      f16x8 Bhi = *(const f16x8*)&hiL[idx];
      f16x8 Blo = *(const f16x8*)&loL[idx];
      #pragma unroll
      for (int ii = 0; ii < 2; ++ii) {
        acc[ii][jt] = __builtin_amdgcn_mfma_f32_16x16x32_f16(Ahi[ii], Bhi, acc[ii][jt], 0, 0, 0);
        acc[ii][jt] = __builtin_amdgcn_mfma_f32_16x16x32_f16(Ahi[ii], Blo, acc[ii][jt], 0, 0, 0);
        acc[ii][jt] = __builtin_amdgcn_mfma_f32_16x16x32_f16(Alo[ii], Bhi, acc[ii][jt], 0, 0, 0);
      }
    }
    __syncthreads();
  }
  float* gp = gpart + ((size_t)n * spb + ks) * 65536;
  #pragma unroll
  for (int ii = 0; ii < 2; ++ii)
    #pragma unroll
    for (int jt = 0; jt < 16; ++jt) {
      int col = jt * 16 + (l & 15);
      int rb  = (i0 + ii) * 16 + ((l >> 4) << 2);
      #pragma unroll
      for (int r = 0; r < 4; ++r)
        gp[(rb + r) * 256 + col] = acc[ii][jt][r];
    }
  ssum += __shfl_xor(ssum, 1);
  if ((t & 1) == 0) spart[((size_t)n * spb + ks) * 256 + c] = ssum;
}

// ---------------------------------------------------------------------------
// K1b: reduce split-K partials -> G (2x256x256), s (2x256); also WkT transpose.
// grid = 770 blocks x 256 threads.
// ---------------------------------------------------------------------------
__global__ __launch_bounds__(256) void reduce_kernel(const float* __restrict__ gpart,
    const float* __restrict__ spart, const float* __restrict__ Wk,
    float* __restrict__ G, float* __restrict__ sv, float* __restrict__ WkT,
    int spb) {
  const int b = blockIdx.x, t = threadIdx.x;
  if (b < 512) {
    int idx = b * 256 + t;
    int n = idx >> 16, e = idx & 65535;
    const float* p = gpart + (size_t)n * spb * 65536 + e;
    float s = 0.f;
    for (int k = 0; k < spb; ++k) s += p[(size_t)k * 65536];
    G[idx] = s;
  } else if (b < 514) {
    int r = (b - 512) * 256 + t;     // 0..511
    int n = r >> 8, cc = r & 255;
    const float* p = spart + (size_t)n * spb * 256 + cc;
    float s = 0.f;
    for (int k = 0; k < spb; ++k) s += p[k * 256];
    sv[r] = s;
  } else {
    int c = b - 514;                 // 0..255: WkT[c][t] = Wk[t][c]
    WkT[c * 256 + t] = Wk[t * 256 + c];
  }
}

// ---------------------------------------------------------------------------
// K2: one wave per (n, j). All vector loads coalesced (float4/lane along t),
// all weight scalars wave-uniform (s_load). Wave-local softmax, no barriers.
//   stage1: t1[t]   = sum_c Wq[j][c] * G[c][t]
//   stage2: S[t]    = sum_c t1[c]*WkT[c][t] + bq[j]*(Wk s)[t] + (wq.s)*bk[t] + M*bq[j]*bk[t]
//   stage3: Bm[j][t]= sum_c att[c] * Wv[c][t]   (bf16)
// ---------------------------------------------------------------------------
__global__ __launch_bounds__(64) void attn_kernel(const float* __restrict__ G,
    const float* __restrict__ sv_g, const float* __restrict__ WkT,
    const float* __restrict__ Wq, const float* __restrict__ bq,
    const float* __restrict__ bk,
    const float* __restrict__ Wv, const float* __restrict__ bv,
    unsigned short* __restrict__ Bm, float* __restrict__ bb) {
  __shared__ float t1_s[256];
  __shared__ float att_s[256];
  const int l = threadIdx.x;                    // 0..63
  const int b = blockIdx.x;                     // 0..511
  const int n = b >> 8, j = b & 255;            // uniform (SGPR)
  const float* Gn  = G + (size_t)n * 65536;
  const float* sn  = sv_g + n * 256;
  const float* wqj = Wq + (size_t)j * 256;
  const int t4 = l << 2;

  // prologue: z2 = wq_j . s
  float4 wq4 = *(const float4*)(wqj + t4);
  float4 sl4 = *(const float4*)(sn + t4);
  float z2 = wq4.x * sl4.x + wq4.y * sl4.y + wq4.z * sl4.z + wq4.w * sl4.w;
  #pragma unroll
  for (int o = 1; o < 64; o <<= 1) z2 += __shfl_xor(z2, o);

  // stage 1: T1 row j
  float4 a = {0.f, 0.f, 0.f, 0.f};
  #pragma unroll 8
  for (int cc = 0; cc < 256; ++cc) {
    float w = wqj[cc];                                   // s_load
    float4 g = *(const float4*)(Gn + (size_t)cc * 256 + t4);
    a.x += w * g.x; a.y += w * g.y; a.z += w * g.z; a.w += w * g.w;
  }
  *(float4*)(t1_s + t4) = a;
  __syncthreads();

  // stage 2: S row + softmax
  float4 ac = {0.f, 0.f, 0.f, 0.f}, a2 = {0.f, 0.f, 0.f, 0.f};
  #pragma unroll 8
  for (int cc = 0; cc < 256; ++cc) {
    float t1v = t1_s[cc];                                // LDS broadcast
    float sc  = sn[cc];                                  // s_load
    float4 k4 = *(const float4*)(WkT + (size_t)cc * 256 + t4);
    ac.x += t1v * k4.x; ac.y += t1v * k4.y; ac.z += t1v * k4.z; ac.w += t1v * k4.w;
    a2.x += sc  * k4.x; a2.y += sc  * k4.y; a2.z += sc  * k4.z; a2.w += sc  * k4.w;
  }
  const float bqj = bq[j];
  float4 bk4 = *(const float4*)(bk + t4);
  float4 S;
  S.x = ac.x + bqj * a2.x + (z2 + 32768.0f * bqj) * bk4.x;
  S.y = ac.y + bqj * a2.y + (z2 + 32768.0f * bqj) * bk4.y;
  S.z = ac.z + bqj * a2.z + (z2 + 32768.0f * bqj) * bk4.z;
  S.w = ac.w + bqj * a2.w + (z2 + 32768.0f * bqj) * bk4.w;

  float mx = fmaxf(fmaxf(S.x, S.y), fmaxf(S.z, S.w));
  #pragma unroll
  for (int o = 1; o < 64; o <<= 1) mx = fmaxf(mx, __shfl_xor(mx, o));
  float4 e;
  e.x = expf(S.x - mx); e.y = expf(S.y - mx);
  e.z = expf(S.z - mx); e.w = expf(S.w - mx);
  float sm = e.x + e.y + e.z + e.w;
  #pragma unroll
  for (int o = 1; o < 64; o <<= 1) sm += __shfl_xor(sm, o);
  float inv = 1.0f / sm;
  float4 att = {e.x * inv, e.y * inv, e.z * inv, e.w * inv};

  // bb[j] = att . bv
  float4 bv4 = *(const float4*)(bv + t4);
  float bbv = att.x * bv4.x + att.y * bv4.y + att.z * bv4.z + att.w * bv4.w;
  #pragma unroll
  for (int o = 1; o < 64; o <<= 1) bbv += __shfl_xor(bbv, o);
  if (l == 0) bb[n * 256 + j] = bbv;

  *(float4*)(att_s + t4) = att;
  __syncthreads();

  // stage 3: Bmat row j
  float4 ov = {0.f, 0.f, 0.f, 0.f};
  #pragma unroll 8
  for (int cc = 0; cc < 256; ++cc) {
    float av = att_s[cc];                                // LDS broadcast
    float4 wv4 = *(const float4*)(Wv + (size_t)cc * 256 + t4);
    ov.x += av * wv4.x; ov.y += av * wv4.y; ov.z += av * wv4.z; ov.w += av * wv4.w;
  }
  ushort4 r;
  r.x = f2bf(ov.x); r.y = f2bf(ov.y); r.z = f2bf(ov.z); r.w = f2bf(ov.w);
  *(ushort4*)(Bm + ((size_t)(n * 256 + j)) * 256 + t4) = r;
}

// ---------------------------------------------------------------------------
// K3: out[n][m][j] = sum_c Bmat[j][c] * X[c][m] + bb[j]   (bf16 MFMA)
// grid = 1024 (n = b>>9, m-block of 64), 256 threads (4 waves, 16 m each).
// ---------------------------------------------------------------------------
__global__ __launch_bounds__(256) void out_kernel(const float* __restrict__ x,
    const unsigned short* __restrict__ Bm, const float* __restrict__ bb,
    float* __restrict__ out) {
  __shared__ unsigned short Bl[256 * 64];
  const int t = threadIdx.x;
  const int b = blockIdx.x;
  const int n = b >> 9, mb = b & 511;
  const int m0 = mb << 6;
  const int l = t & 63, w = t >> 6;
  f32x4 acc[16];
  #pragma unroll
  for (int jt = 0; jt < 16; ++jt) acc[jt] = (f32x4){0.f, 0.f, 0.f, 0.f};
  const unsigned short* Bmn = Bm + (size_t)n * 65536;
  const float* xn = x + (size_t)n * CCH * MM;
  const int mA = m0 + w * 16 + (l & 15);
  for (int ch = 0; ch < 4; ++ch) {
    #pragma unroll
    for (int it = 0; it < 8; ++it) {      // stage Bmat[:, ch*64 .. +64) bf16
      int i = it * 256 + t;
      int j = i >> 3, cb = i & 7;
      uint4 v = *(const uint4*)(Bmn + (size_t)j * 256 + ch * 64 + cb * 8);
      int slot = cb ^ (j & 7);
      *(uint4*)&Bl[j * 64 + slot * 8] = v;
    }
    __syncthreads();
    #pragma unroll
    for (int kk = 0; kk < 2; ++kk) {
      int cbase = ch * 64 + kk * 32 + (l >> 4) * 8;
      const float* xp = xn + (size_t)cbase * MM + mA;
      bf16x8 afrag;
      #pragma unroll
      for (int jj = 0; jj < 8; ++jj) {
        float v = xp[(size_t)jj * MM];
        afrag[jj] = (short)f2bf(v);
      }
      int cb2 = kk * 4 + (l >> 4);
      #pragma unroll
      for (int jt = 0; jt < 16; ++jt) {
        int jrow = jt * 16 + (l & 15);
        int slot = cb2 ^ (jrow & 7);
        bf16x8 bfrag = *(const bf16x8*)&Bl[jrow * 64 + slot * 8];
        acc[jt] = __builtin_amdgcn_mfma_f32_16x16x32_bf16(afrag, bfrag, acc[jt], 0, 0, 0);
      }
    }
    __syncthreads();
  }
  float* op = out + (size_t)n * MM * 256;
  const int mrb = m0 + w * 16 + ((l >> 4) << 2);
  #pragma unroll
  for (int jt = 0; jt < 16; ++jt) {
    int jcol = jt * 16 + (l & 15);
    float bias = bb[n * 256 + jcol];
    #pragma unroll
    for (int r = 0; r < 4; ++r)
      op[(size_t)(mrb + r) * 256 + jcol] = acc[jt][r] + bias;
  }
}

// ---------------------------------------------------------------------------
extern "C" void kernel_launch(void* const* d_in, const int* in_sizes, int n_in,
                              void* d_out, int out_size, void* d_ws, size_t ws_size,
                              hipStream_t stream) {
  (void)in_sizes; (void)n_in; (void)out_size;
  const float* x  = (const float*)d_in[0];
  const float* Wq = (const float*)d_in[1];
  const float* bq = (const float*)d_in[2];
  const float* Wk = (const float*)d_in[3];
  const float* bk = (const float*)d_in[4];
  const float* Wv = (const float*)d_in[5];
  const float* bv = (const float*)d_in[6];
  float* out = (float*)d_out;

  // split-K factor: largest power of two <= 128 whose workspace fits
  int spb = 128;
  while (spb > 1) {
    size_t need = ((size_t)2 * spb * (65536 + 256) + 2 * 65536 + 512 + 512 + 65536) * 4
                + (size_t)2 * 65536 * 2;
    if (need <= ws_size) break;
    spb >>= 1;
  }
  float* wsf   = (float*)d_ws;
  float* gpart = wsf;
  float* spart = gpart + (size_t)2 * spb * 65536;
  float* G     = spart + (size_t)2 * spb * 256;
  float* sv    = G + 2 * 65536;
  float* bb    = sv + 512;
  float* WkT   = bb + 512;
  unsigned short* Bm = (unsigned short*)(WkT + 65536);
  const int Mc = MM / spb;

  gram_kernel<<<dim3(2 * spb), dim3(512), 0, stream>>>(x, gpart, spart, Mc, spb);
  reduce_kernel<<<dim3(770), dim3(256), 0, stream>>>(gpart, spart, Wk, G, sv, WkT, spb);
  attn_kernel<<<dim3(512), dim3(64), 0, stream>>>(G, sv, WkT, Wq, bq, bk, Wv, bv, Bm, bb);
  out_kernel<<<dim3(1024), dim3(256), 0, stream>>>(x, Bm, bb, out);
}